// Round 12
// baseline (131.717 us; speedup 1.0000x reference)
//
#include <hip/hip_runtime.h>
#include <hip/hip_bf16.h>

typedef __attribute__((ext_vector_type(8))) short short8;
typedef __attribute__((ext_vector_type(4))) float f32x4;
typedef __attribute__((ext_vector_type(4))) unsigned int u32x4;

#define GG 4
#define CC 128
#define HH 112
#define WW 112
#define HWSZ (HH * WW)
#define TH 16
#define TW 16
#define HALO 18
#define NPIX (HALO * HALO)      // 324
#define XSTR 40                 // bf16 per pixel row in LDS: pad 32->40 (80B; b128 reads ~conflict-free)
#define WK_ELEMS (4 * 9 * 16 * 32)   // wk_reord[g][u][t16][c32], taps 9..15 zero
#define WP_ELEMS (4 * 2 * 16 * 32)   // wp_reord[g][mt][o16][c32]
#define W_TOTAL (WK_ELEMS + WP_ELEMS)
#define XT_OFF 32768                 // ushort offset of x_t in ws
#define XT_ELEMS (8 * 4 * HWSZ * 32)
#define WS_NEED ((size_t)(XT_OFF + XT_ELEMS) * 2)

__device__ __forceinline__ void reorder_one(int idx,
    const float* __restrict__ w_kg, const float* __restrict__ w_pw,
    unsigned short* __restrict__ ws)
{
    if (idx < WK_ELEMS) {
        int c = idx & 31, t = (idx >> 5) & 15, r = idx >> 9;
        int u = r % 9, g = r / 9;
        float v = (t < 9) ? w_kg[((g * 9 + t) * 32 + c) * 9 + u] : 0.0f;
        ws[idx] = __builtin_bit_cast(unsigned short, __float2bfloat16(v));
    } else if (idx < W_TOTAL) {
        int j = idx - WK_ELEMS;
        int c = j & 31, o = (j >> 5) & 15, mt = (j >> 9) & 1, g = j >> 10;
        float v = w_pw[(g * 32 + mt * 16 + o) * 32 + c];
        ws[idx] = __builtin_bit_cast(unsigned short, __float2bfloat16(v));
    }
}

// ---- standalone weight reorder (fallback path only) ----
__global__ __launch_bounds__(256)
void reorder_weights(const float* __restrict__ w_kg, const float* __restrict__ w_pw,
                     unsigned short* __restrict__ ws)
{
    reorder_one(blockIdx.x * 256 + threadIdx.x, w_kg, w_pw, ws);
}

// ---- transpose x -> x_t[b][g][pixel][c32] bf16; hc==28 blocks do weight reorder ----
__global__ __launch_bounds__(256, 4)
void transpose_x(const float* __restrict__ x,
                 const float* __restrict__ w_kg, const float* __restrict__ w_pw,
                 unsigned short* __restrict__ ws)
{
    __shared__ unsigned int xsT[16 * 452];       // [c2][p448] u32 = 2 channels; 28,928 B
    const int hc = blockIdx.x;                   // 0..27 transpose chunks; 28 = weights
    const int g = blockIdx.y, b = blockIdx.z;
    const int tid = threadIdx.x;

    if (hc == 28) {                              // 32 slices x 704 = 22,528 weight elems
        const int slice = b * GG + g;
        #pragma unroll
        for (int k = 0; k < 3; ++k) {
            int off = k * 256 + tid;
            if (off < 704)
                reorder_one(slice * 704 + off, w_kg, w_pw, ws);
        }
        return;
    }

    const float* xg = x + (size_t)(b * CC + g * 32) * HWSZ + hc * 4 * WW;
    unsigned short* xt = ws + XT_OFF;

    // phase 1: coalesced float4 reads (c-major, pixel-fastest), cvt, b16 LDS writes
    // into the u32 [c2][p] layout (channel parity selects lo/hi half)
    unsigned short* xsT16 = (unsigned short*)xsT;
    #pragma unroll
    for (int k = 0; k < 14; ++k) {               // 3584 tasks = 32c x 112 p4-groups
        int t = tid + 256 * k;
        int c = (t * 37450) >> 22;               // t/112, exact for t<3584
        int p4 = t - c * 112;
        float4 v = *(const float4*)(xg + (size_t)c * HWSZ + 4 * p4);
        int base = ((c >> 1) * 452 + 4 * p4) * 2 + (c & 1);
        xsT16[base + 0] = __builtin_bit_cast(unsigned short, __float2bfloat16(v.x));
        xsT16[base + 2] = __builtin_bit_cast(unsigned short, __float2bfloat16(v.y));
        xsT16[base + 4] = __builtin_bit_cast(unsigned short, __float2bfloat16(v.z));
        xsT16[base + 6] = __builtin_bit_cast(unsigned short, __float2bfloat16(v.w));
    }
    __syncthreads();

    // phase 2: gather 4 u32 (8 channels)/pixel-chunk, write contiguous 16B
    unsigned short* xto = xt + ((size_t)(b * GG + g) * HWSZ + (size_t)hc * 448) * 32;
    #pragma unroll
    for (int k = 0; k < 7; ++k) {                // 1792 tasks = 448 px x 4 kb-chunks
        int t = tid + 256 * k;
        int p = t >> 2, kb = t & 3;
        unsigned r[4];
        #pragma unroll
        for (int j = 0; j < 4; ++j)
            r[j] = xsT[(4 * kb + j) * 452 + p];  // u32 = channels (8kb+2j, 8kb+2j+1)
        *(u32x4*)(xto + (size_t)t * 8) = (u32x4){r[0], r[1], r[2], r[3]};
    }
}

// ---- per-thread weight fragments, loaded BEFORE staging (overlap global latency) ----
struct Frags {
    short8 afrag[9];
    short8 wpfrag[2];
    float bkv[4];
    float bpv[8];
};

__device__ __forceinline__ void load_frags(Frags& f,
    const unsigned short* __restrict__ wsw,
    const float* __restrict__ b_kg, const float* __restrict__ b_pw,
    int g, int tid)
{
    const int lane = tid & 63;
    const int px   = lane & 15;
    const int kb   = lane >> 4;

    #pragma unroll
    for (int u = 0; u < 9; ++u)
        f.afrag[u] = *(const short8*)(wsw + (((g * 9 + u) * 16 + px) * 32 + kb * 8));
    #pragma unroll
    for (int mt = 0; mt < 2; ++mt)
        f.wpfrag[mt] = *(const short8*)(wsw + WK_ELEMS + (((g * 2 + mt) * 16 + px) * 32 + kb * 8));

    const float* bk = b_kg + g * 9;
    const float* bp = b_pw + g * 32;
    #pragma unroll
    for (int e = 0; e < 4; ++e) {
        int t = 4 * kb + e;
        f.bkv[e] = bk[t < 9 ? t : 0];   // clamped; invalid taps never consumed
    }
    #pragma unroll
    for (int mt = 0; mt < 2; ++mt)
        #pragma unroll
        for (int e = 0; e < 4; ++e)
            f.bpv[mt * 4 + e] = bp[mt * 16 + 4 * kb + e];
}

// ---- compute body (proven kvl-roundtrip kv broadcast; NO ds_bpermute — r5/r9
//      A/B pinned a deterministic miscompute on bpermute-after-MFMA) ----
// NWAVES waves per block; each wave owns 16/NWAVES consecutive pixel rows.
template<int NWAVES>
__device__ __forceinline__ void compute_tile(const Frags& f,
    float* __restrict__ out, unsigned short* xs, float* kvl,
    int g, int b, int h0, int w0, int tid)
{
    const int lane = tid & 63;
    const int wid  = tid >> 6;
    const int px   = lane & 15;
    const int kb   = lane >> 4;
    const int RPW  = 16 / NWAVES;

    float* kvp = &kvl[(wid * 16 + px) * 12];
    const size_t obase = ((size_t)(b * CC + g * 32) * HH + h0) * WW + w0 + px;

    #pragma unroll 1
    for (int r = 0; r < RPW; ++r) {
        const int py = wid * RPW + r;

        short8 bfrag[9];
        #pragma unroll
        for (int u = 0; u < 9; ++u) {
            int q = (py + u / 3) * HALO + (px + u % 3);
            bfrag[u] = *(const short8*)&xs[q * XSTR + kb * 8];
        }

        // stage 1: kv = Wk * P; C/D: col=lane&15 (pixel), row=4*kb+e (tap)
        f32x4 kv = {0.f, 0.f, 0.f, 0.f};
        #pragma unroll
        for (int u = 0; u < 9; ++u)
            kv = __builtin_amdgcn_mfma_f32_16x16x32_bf16(f.afrag[u], bfrag[u], kv, 0, 0, 0);

        // kv cross-lane roundtrip (+bias): lane holds taps 4*kb..4*kb+3 of pixel px
        if (kb < 2) {
            f32x4 kvb;
            #pragma unroll
            for (int i = 0; i < 4; ++i) kvb[i] = kv[i] + f.bkv[i];
            *(f32x4*)&kvp[4 * kb] = kvb;
        } else if (kb == 2) {
            kvp[8] = kv[0] + f.bkv[0];
        }
        f32x4 k03 = *(const f32x4*)&kvp[0];
        f32x4 k47 = *(const f32x4*)&kvp[4];
        float k8 = kvp[8];
        float kvv[9] = {k03.x, k03.y, k03.z, k03.w, k47.x, k47.y, k47.z, k47.w, k8};

        // stage 2: involution on VALU, reusing bfrag registers
        float m[8] = {0.f, 0.f, 0.f, 0.f, 0.f, 0.f, 0.f, 0.f};
        #pragma unroll
        for (int u = 0; u < 9; ++u) {
            u32x4 bu = __builtin_bit_cast(u32x4, bfrag[u]);
            #pragma unroll
            for (int w = 0; w < 4; ++w) {
                unsigned d = bu[w];
                float lo = __builtin_bit_cast(float, d << 16);
                float hi = __builtin_bit_cast(float, d & 0xffff0000u);
                m[2 * w]     = fmaf(lo, kvv[u], m[2 * w]);
                m[2 * w + 1] = fmaf(hi, kvv[u], m[2 * w + 1]);
            }
        }

        // stage 3: pointwise via MFMA; m already in B-fragment order (k = 8kb+j)
        unsigned pk[4];
        #pragma unroll
        for (int w = 0; w < 4; ++w) {
            unsigned slo = __builtin_bit_cast(unsigned short, __float2bfloat16(m[2 * w]));
            unsigned shi = __builtin_bit_cast(unsigned short, __float2bfloat16(m[2 * w + 1]));
            pk[w] = slo | (shi << 16);
        }
        short8 mfrag = __builtin_bit_cast(short8, (u32x4){pk[0], pk[1], pk[2], pk[3]});

        f32x4 zero = {0.f, 0.f, 0.f, 0.f};
        f32x4 o0 = __builtin_amdgcn_mfma_f32_16x16x32_bf16(f.wpfrag[0], mfrag, zero, 0, 0, 0);
        f32x4 o1 = __builtin_amdgcn_mfma_f32_16x16x32_bf16(f.wpfrag[1], mfrag, zero, 0, 0, 0);

        #pragma unroll
        for (int e = 0; e < 4; ++e) {
            int o = 4 * kb + e;
            out[obase + (size_t)o * HWSZ + (size_t)py * WW] = o0[e] + f.bpv[e];
            out[obase + (size_t)(o + 16) * HWSZ + (size_t)py * WW] = o1[e] + f.bpv[4 + e];
        }
    }
}

// ---- fast main kernel: 512 threads (8 waves, 2 rows each) for 32 waves/CU ----
__global__ __launch_bounds__(512, 8)
void invol_mfma(const unsigned short* __restrict__ ws_all,
                const float* __restrict__ b_kg, const float* __restrict__ b_pw,
                float* __restrict__ out)
{
    __shared__ unsigned short xs[NPIX * XSTR];   // 25,920 B
    __shared__ float kvl[8 * 16 * 12];           //  6,144 B -> 4 blocks/CU (HW wave cap)

    const int tile  = blockIdx.x;
    const int tileh = tile / 7;
    const int tilew = tile - tileh * 7;
    const int g = blockIdx.y;
    const int b = blockIdx.z;
    const int h0 = tileh * TH;
    const int w0 = tilew * TW;
    const int tid = threadIdx.x;

    // weight fragments first: global latency overlaps the staging phase below
    Frags f;
    load_frags(f, ws_all, b_kg, b_pw, g, tid);

    // staging: 1296 x 16B tasks from x_t (channel-contiguous, coalesced runs)
    {
        const unsigned short* xti = ws_all + XT_OFF + (size_t)(b * GG + g) * HWSZ * 32;
        u32x4 vals[3];
        int lidx[3];
        #pragma unroll
        for (int k = 0; k < 3; ++k) {
            int t = tid + 512 * k;
            bool valid = (k < 2) || (t < 1296);
            int tc = valid ? t : 1295;
            int q = tc >> 2, kb2 = tc & 3;
            int r = (q * 57) >> 10;              // q/18 for q<324
            int col = q - 18 * r;
            int gh = h0 - 1 + r, gw = w0 - 1 + col;
            bool ok = valid && ((unsigned)gh < (unsigned)HH) && ((unsigned)gw < (unsigned)WW);
            int ghc = min(max(gh, 0), HH - 1);
            int gwc = min(max(gw, 0), WW - 1);
            u32x4 v = *(const u32x4*)(xti + ((size_t)(ghc * WW + gwc) * 32 + kb2 * 8));
            vals[k] = ok ? v : (u32x4){0, 0, 0, 0};
            lidx[k] = q * XSTR + kb2 * 8;
        }
        #pragma unroll
        for (int k = 0; k < 3; ++k) {
            int t = tid + 512 * k;
            if ((k < 2) || (t < 1296))
                *(short8*)&xs[lidx[k]] = __builtin_bit_cast(short8, vals[k]);
        }
    }
    __syncthreads();

    compute_tile<8>(f, out, xs, kvl, g, b, h0, w0, tid);
}

// ---- fallback main kernel (direct fp32 staging, 256 threads) for small ws ----
__global__ __launch_bounds__(256, 4)
void invol_mfma_fb(const float* __restrict__ x,
                   const float* __restrict__ b_kg, const float* __restrict__ b_pw,
                   const unsigned short* __restrict__ ws, float* __restrict__ out)
{
    __shared__ unsigned short xs[NPIX * XSTR];
    __shared__ float kvl[4 * 16 * 12];

    const int tile  = blockIdx.x;
    const int tileh = tile / 7;
    const int tilew = tile - tileh * 7;
    const int g = blockIdx.y;
    const int b = blockIdx.z;
    const int h0 = tileh * TH;
    const int w0 = tilew * TW;
    const int tid = threadIdx.x;

    Frags f;
    load_frags(f, ws, b_kg, b_pw, g, tid);

    {
        const float* xg = x + (size_t)(b * CC + g * 32) * HWSZ;
        int c = 0, q = tid;
        #pragma unroll
        for (int batch = 0; batch < 3; ++batch) {
            const int bn = (batch == 2) ? 13 : 14;
            float v[14];
            int pki[14];
            #pragma unroll
            for (int it = 0; it < bn; ++it) {
                const int itg = batch * 14 + it;
                const bool valid = (itg < 40) || (tid < 128);
                int r   = (q * 57) >> 10;
                int col = q - 18 * r;
                int gh = h0 - 1 + r;
                int gw = w0 - 1 + col;
                bool ok = valid && ((unsigned)gh < (unsigned)HH) && ((unsigned)gw < (unsigned)WW);
                int ghc = min(max(gh, 0), HH - 1);
                int gwc = min(max(gw, 0), WW - 1);
                int cc  = min(c, 31);
                float t = xg[(size_t)cc * HWSZ + ghc * WW + gwc];
                v[it]   = ok ? t : 0.0f;
                pki[it] = q * XSTR + c;
                q += 256; if (q >= NPIX) { q -= NPIX; ++c; }
            }
            #pragma unroll
            for (int it = 0; it < bn; ++it)
                xs[pki[it]] = __builtin_bit_cast(unsigned short, __float2bfloat16(v[it]));
        }
    }
    __syncthreads();

    compute_tile<4>(f, out, xs, kvl, g, b, h0, w0, tid);
}

extern "C" void kernel_launch(void* const* d_in, const int* in_sizes, int n_in,
                              void* d_out, int out_size, void* d_ws, size_t ws_size,
                              hipStream_t stream)
{
    const float* x    = (const float*)d_in[0];
    const float* w_kg = (const float*)d_in[1];
    const float* b_kg = (const float*)d_in[2];
    const float* w_pw = (const float*)d_in[3];
    const float* b_pw = (const float*)d_in[4];
    float* out = (float*)d_out;
    unsigned short* ws = (unsigned short*)d_ws;

    if (ws_size >= WS_NEED) {
        hipLaunchKernelGGL(transpose_x, dim3(29, GG, 8), dim3(256), 0, stream,
                           x, w_kg, w_pw, ws);
        hipLaunchKernelGGL(invol_mfma, dim3(49, GG, 8), dim3(512), 0, stream,
                           ws, b_kg, b_pw, out);
    } else {
        int pre_blocks = (W_TOTAL + 255) / 256;
        hipLaunchKernelGGL(reorder_weights, dim3(pre_blocks), dim3(256), 0, stream,
                           w_kg, w_pw, ws);
        hipLaunchKernelGGL(invol_mfma_fb, dim3(49, GG, 8), dim3(256), 0, stream,
                           x, b_kg, b_pw, ws, out);
    }
}

// Round 13
// 46.468 us; speedup vs baseline: 2.8346x; 2.8346x over previous
//
#include <hip/hip_runtime.h>
#include <hip/hip_bf16.h>

typedef __attribute__((ext_vector_type(8))) short short8;
typedef __attribute__((ext_vector_type(4))) float f32x4;
typedef __attribute__((ext_vector_type(4))) unsigned int u32x4;

#define GG 4
#define CC 128
#define HH 112
#define WW 112
#define HWSZ (HH * WW)
#define TH 16
#define TW 16
#define HALO 18
#define NPIX (HALO * HALO)      // 324
#define XSTR 40                 // bf16 per pixel row in LDS: pad 32->40 (80B; b128 reads ~conflict-free)
#define WK_ELEMS (4 * 9 * 16 * 32)   // wk_reord[g][u][t16][c32], taps 9..15 zero
#define WP_ELEMS (4 * 2 * 16 * 32)   // wp_reord[g][mt][o16][c32]
#define W_TOTAL (WK_ELEMS + WP_ELEMS)
#define XT_OFF 32768                 // ushort offset of x_t in ws
#define XT_ELEMS (8 * 4 * HWSZ * 32)
#define WS_NEED ((size_t)(XT_OFF + XT_ELEMS) * 2)

__device__ __forceinline__ void reorder_one(int idx,
    const float* __restrict__ w_kg, const float* __restrict__ w_pw,
    unsigned short* __restrict__ ws)
{
    if (idx < WK_ELEMS) {
        int c = idx & 31, t = (idx >> 5) & 15, r = idx >> 9;
        int u = r % 9, g = r / 9;
        float v = (t < 9) ? w_kg[((g * 9 + t) * 32 + c) * 9 + u] : 0.0f;
        ws[idx] = __builtin_bit_cast(unsigned short, __float2bfloat16(v));
    } else if (idx < W_TOTAL) {
        int j = idx - WK_ELEMS;
        int c = j & 31, o = (j >> 5) & 15, mt = (j >> 9) & 1, g = j >> 10;
        float v = w_pw[(g * 32 + mt * 16 + o) * 32 + c];
        ws[idx] = __builtin_bit_cast(unsigned short, __float2bfloat16(v));
    }
}

// ---- standalone weight reorder (fallback path only) ----
__global__ __launch_bounds__(256)
void reorder_weights(const float* __restrict__ w_kg, const float* __restrict__ w_pw,
                     unsigned short* __restrict__ ws)
{
    reorder_one(blockIdx.x * 256 + threadIdx.x, w_kg, w_pw, ws);
}

// ---- transpose x -> x_t[b][g][pixel][c32] bf16; hc==28 blocks do weight reorder ----
__global__ __launch_bounds__(256, 4)
void transpose_x(const float* __restrict__ x,
                 const float* __restrict__ w_kg, const float* __restrict__ w_pw,
                 unsigned short* __restrict__ ws)
{
    __shared__ unsigned int xsT[16 * 452];       // [c2][p448] u32 = 2 channels; 28,928 B
    const int hc = blockIdx.x;                   // 0..27 transpose chunks; 28 = weights
    const int g = blockIdx.y, b = blockIdx.z;
    const int tid = threadIdx.x;

    if (hc == 28) {                              // 32 slices x 704 = 22,528 weight elems
        const int slice = b * GG + g;
        #pragma unroll
        for (int k = 0; k < 3; ++k) {
            int off = k * 256 + tid;
            if (off < 704)
                reorder_one(slice * 704 + off, w_kg, w_pw, ws);
        }
        return;
    }

    const float* xg = x + (size_t)(b * CC + g * 32) * HWSZ + hc * 4 * WW;
    unsigned short* xt = ws + XT_OFF;

    // phase 1: coalesced float4 reads (c-major, pixel-fastest), cvt, b16 LDS writes
    // into the u32 [c2][p] layout (channel parity selects lo/hi half)
    unsigned short* xsT16 = (unsigned short*)xsT;
    #pragma unroll
    for (int k = 0; k < 14; ++k) {               // 3584 tasks = 32c x 112 p4-groups
        int t = tid + 256 * k;
        int c = (t * 37450) >> 22;               // t/112, exact for t<3584
        int p4 = t - c * 112;
        float4 v = *(const float4*)(xg + (size_t)c * HWSZ + 4 * p4);
        int base = ((c >> 1) * 452 + 4 * p4) * 2 + (c & 1);
        xsT16[base + 0] = __builtin_bit_cast(unsigned short, __float2bfloat16(v.x));
        xsT16[base + 2] = __builtin_bit_cast(unsigned short, __float2bfloat16(v.y));
        xsT16[base + 4] = __builtin_bit_cast(unsigned short, __float2bfloat16(v.z));
        xsT16[base + 6] = __builtin_bit_cast(unsigned short, __float2bfloat16(v.w));
    }
    __syncthreads();

    // phase 2: gather 4 u32 (8 channels)/pixel-chunk, write contiguous 16B
    unsigned short* xto = xt + ((size_t)(b * GG + g) * HWSZ + (size_t)hc * 448) * 32;
    #pragma unroll
    for (int k = 0; k < 7; ++k) {                // 1792 tasks = 448 px x 4 kb-chunks
        int t = tid + 256 * k;
        int p = t >> 2, kb = t & 3;
        unsigned r[4];
        #pragma unroll
        for (int j = 0; j < 4; ++j)
            r[j] = xsT[(4 * kb + j) * 452 + p];  // u32 = channels (8kb+2j, 8kb+2j+1)
        *(u32x4*)(xto + (size_t)t * 8) = (u32x4){r[0], r[1], r[2], r[3]};
    }
}

// ---- per-thread weight fragments, loaded BEFORE staging (overlap global latency) ----
struct Frags {
    short8 afrag[9];
    short8 wpfrag[2];
    float bkv[4];
    float bpv[8];
};

__device__ __forceinline__ void load_frags(Frags& f,
    const unsigned short* __restrict__ wsw,
    const float* __restrict__ b_kg, const float* __restrict__ b_pw,
    int g, int tid)
{
    const int lane = tid & 63;
    const int px   = lane & 15;
    const int kb   = lane >> 4;

    #pragma unroll
    for (int u = 0; u < 9; ++u)
        f.afrag[u] = *(const short8*)(wsw + (((g * 9 + u) * 16 + px) * 32 + kb * 8));
    #pragma unroll
    for (int mt = 0; mt < 2; ++mt)
        f.wpfrag[mt] = *(const short8*)(wsw + WK_ELEMS + (((g * 2 + mt) * 16 + px) * 32 + kb * 8));

    const float* bk = b_kg + g * 9;
    const float* bp = b_pw + g * 32;
    #pragma unroll
    for (int e = 0; e < 4; ++e) {
        int t = 4 * kb + e;
        f.bkv[e] = bk[t < 9 ? t : 0];   // clamped; invalid taps never consumed
    }
    #pragma unroll
    for (int mt = 0; mt < 2; ++mt)
        #pragma unroll
        for (int e = 0; e < 4; ++e)
            f.bpv[mt * 4 + e] = bp[mt * 16 + 4 * kb + e];
}

// ---- compute body (proven kvl-roundtrip kv broadcast; NO ds_bpermute — r5/r9
//      A/B pinned a deterministic miscompute on bpermute-after-MFMA) ----
// NWAVES waves per block; each wave owns 16/NWAVES consecutive pixel rows.
template<int NWAVES>
__device__ __forceinline__ void compute_tile(const Frags& f,
    float* __restrict__ out, unsigned short* xs, float* kvl,
    int g, int b, int h0, int w0, int tid)
{
    const int lane = tid & 63;
    const int wid  = tid >> 6;
    const int px   = lane & 15;
    const int kb   = lane >> 4;
    const int RPW  = 16 / NWAVES;

    float* kvp = &kvl[(wid * 16 + px) * 12];
    const size_t obase = ((size_t)(b * CC + g * 32) * HH + h0) * WW + w0 + px;

    #pragma unroll 1
    for (int r = 0; r < RPW; ++r) {
        const int py = wid * RPW + r;

        short8 bfrag[9];
        #pragma unroll
        for (int u = 0; u < 9; ++u) {
            int q = (py + u / 3) * HALO + (px + u % 3);
            bfrag[u] = *(const short8*)&xs[q * XSTR + kb * 8];
        }

        // stage 1: kv = Wk * P; C/D: col=lane&15 (pixel), row=4*kb+e (tap)
        f32x4 kv = {0.f, 0.f, 0.f, 0.f};
        #pragma unroll
        for (int u = 0; u < 9; ++u)
            kv = __builtin_amdgcn_mfma_f32_16x16x32_bf16(f.afrag[u], bfrag[u], kv, 0, 0, 0);

        // kv cross-lane roundtrip (+bias): lane holds taps 4*kb..4*kb+3 of pixel px
        if (kb < 2) {
            f32x4 kvb;
            #pragma unroll
            for (int i = 0; i < 4; ++i) kvb[i] = kv[i] + f.bkv[i];
            *(f32x4*)&kvp[4 * kb] = kvb;
        } else if (kb == 2) {
            kvp[8] = kv[0] + f.bkv[0];
        }
        f32x4 k03 = *(const f32x4*)&kvp[0];
        f32x4 k47 = *(const f32x4*)&kvp[4];
        float k8 = kvp[8];
        float kvv[9] = {k03.x, k03.y, k03.z, k03.w, k47.x, k47.y, k47.z, k47.w, k8};

        // stage 2: involution on VALU, reusing bfrag registers
        float m[8] = {0.f, 0.f, 0.f, 0.f, 0.f, 0.f, 0.f, 0.f};
        #pragma unroll
        for (int u = 0; u < 9; ++u) {
            u32x4 bu = __builtin_bit_cast(u32x4, bfrag[u]);
            #pragma unroll
            for (int w = 0; w < 4; ++w) {
                unsigned d = bu[w];
                float lo = __builtin_bit_cast(float, d << 16);
                float hi = __builtin_bit_cast(float, d & 0xffff0000u);
                m[2 * w]     = fmaf(lo, kvv[u], m[2 * w]);
                m[2 * w + 1] = fmaf(hi, kvv[u], m[2 * w + 1]);
            }
        }

        // stage 3: pointwise via MFMA; m already in B-fragment order (k = 8kb+j)
        unsigned pk[4];
        #pragma unroll
        for (int w = 0; w < 4; ++w) {
            unsigned slo = __builtin_bit_cast(unsigned short, __float2bfloat16(m[2 * w]));
            unsigned shi = __builtin_bit_cast(unsigned short, __float2bfloat16(m[2 * w + 1]));
            pk[w] = slo | (shi << 16);
        }
        short8 mfrag = __builtin_bit_cast(short8, (u32x4){pk[0], pk[1], pk[2], pk[3]});

        f32x4 zero = {0.f, 0.f, 0.f, 0.f};
        f32x4 o0 = __builtin_amdgcn_mfma_f32_16x16x32_bf16(f.wpfrag[0], mfrag, zero, 0, 0, 0);
        f32x4 o1 = __builtin_amdgcn_mfma_f32_16x16x32_bf16(f.wpfrag[1], mfrag, zero, 0, 0, 0);

        #pragma unroll
        for (int e = 0; e < 4; ++e) {
            int o = 4 * kb + e;
            out[obase + (size_t)o * HWSZ + (size_t)py * WW] = o0[e] + f.bpv[e];
            out[obase + (size_t)(o + 16) * HWSZ + (size_t)py * WW] = o1[e] + f.bpv[4 + e];
        }
    }
}

// ---- fast main kernel: 512 threads, min-waves=4 -> 128-VGPR budget (NO spill;
//      r12's (512,8) forced a 32-VGPR cap and 210 MB of scratch traffic) ----
__global__ __launch_bounds__(512, 4)
void invol_mfma(const unsigned short* __restrict__ ws_all,
                const float* __restrict__ b_kg, const float* __restrict__ b_pw,
                float* __restrict__ out)
{
    __shared__ unsigned short xs[NPIX * XSTR];   // 25,920 B
    __shared__ float kvl[8 * 16 * 12];           //  6,144 B

    const int tile  = blockIdx.x;
    const int tileh = tile / 7;
    const int tilew = tile - tileh * 7;
    const int g = blockIdx.y;
    const int b = blockIdx.z;
    const int h0 = tileh * TH;
    const int w0 = tilew * TW;
    const int tid = threadIdx.x;

    // weight fragments first: global latency overlaps the staging phase below
    Frags f;
    load_frags(f, ws_all, b_kg, b_pw, g, tid);

    // staging: 1296 x 16B tasks from x_t (channel-contiguous, coalesced runs)
    {
        const unsigned short* xti = ws_all + XT_OFF + (size_t)(b * GG + g) * HWSZ * 32;
        u32x4 vals[3];
        int lidx[3];
        #pragma unroll
        for (int k = 0; k < 3; ++k) {
            int t = tid + 512 * k;
            bool valid = (k < 2) || (t < 1296);
            int tc = valid ? t : 1295;
            int q = tc >> 2, kb2 = tc & 3;
            int r = (q * 57) >> 10;              // q/18 for q<324
            int col = q - 18 * r;
            int gh = h0 - 1 + r, gw = w0 - 1 + col;
            bool ok = valid && ((unsigned)gh < (unsigned)HH) && ((unsigned)gw < (unsigned)WW);
            int ghc = min(max(gh, 0), HH - 1);
            int gwc = min(max(gw, 0), WW - 1);
            u32x4 v = *(const u32x4*)(xti + ((size_t)(ghc * WW + gwc) * 32 + kb2 * 8));
            vals[k] = ok ? v : (u32x4){0, 0, 0, 0};
            lidx[k] = q * XSTR + kb2 * 8;
        }
        #pragma unroll
        for (int k = 0; k < 3; ++k) {
            int t = tid + 512 * k;
            if ((k < 2) || (t < 1296))
                *(short8*)&xs[lidx[k]] = __builtin_bit_cast(short8, vals[k]);
        }
    }
    __syncthreads();

    compute_tile<8>(f, out, xs, kvl, g, b, h0, w0, tid);
}

// ---- fallback main kernel (direct fp32 staging, 256 threads) for small ws ----
__global__ __launch_bounds__(256, 4)
void invol_mfma_fb(const float* __restrict__ x,
                   const float* __restrict__ b_kg, const float* __restrict__ b_pw,
                   const unsigned short* __restrict__ ws, float* __restrict__ out)
{
    __shared__ unsigned short xs[NPIX * XSTR];
    __shared__ float kvl[4 * 16 * 12];

    const int tile  = blockIdx.x;
    const int tileh = tile / 7;
    const int tilew = tile - tileh * 7;
    const int g = blockIdx.y;
    const int b = blockIdx.z;
    const int h0 = tileh * TH;
    const int w0 = tilew * TW;
    const int tid = threadIdx.x;

    Frags f;
    load_frags(f, ws, b_kg, b_pw, g, tid);

    {
        const float* xg = x + (size_t)(b * CC + g * 32) * HWSZ;
        int c = 0, q = tid;
        #pragma unroll
        for (int batch = 0; batch < 3; ++batch) {
            const int bn = (batch == 2) ? 13 : 14;
            float v[14];
            int pki[14];
            #pragma unroll
            for (int it = 0; it < bn; ++it) {
                const int itg = batch * 14 + it;
                const bool valid = (itg < 40) || (tid < 128);
                int r   = (q * 57) >> 10;
                int col = q - 18 * r;
                int gh = h0 - 1 + r;
                int gw = w0 - 1 + col;
                bool ok = valid && ((unsigned)gh < (unsigned)HH) && ((unsigned)gw < (unsigned)WW);
                int ghc = min(max(gh, 0), HH - 1);
                int gwc = min(max(gw, 0), WW - 1);
                int cc  = min(c, 31);
                float t = xg[(size_t)cc * HWSZ + ghc * WW + gwc];
                v[it]   = ok ? t : 0.0f;
                pki[it] = q * XSTR + c;
                q += 256; if (q >= NPIX) { q -= NPIX; ++c; }
            }
            #pragma unroll
            for (int it = 0; it < bn; ++it)
                xs[pki[it]] = __builtin_bit_cast(unsigned short, __float2bfloat16(v[it]));
        }
    }
    __syncthreads();

    compute_tile<4>(f, out, xs, kvl, g, b, h0, w0, tid);
}

extern "C" void kernel_launch(void* const* d_in, const int* in_sizes, int n_in,
                              void* d_out, int out_size, void* d_ws, size_t ws_size,
                              hipStream_t stream)
{
    const float* x    = (const float*)d_in[0];
    const float* w_kg = (const float*)d_in[1];
    const float* b_kg = (const float*)d_in[2];
    const float* w_pw = (const float*)d_in[3];
    const float* b_pw = (const float*)d_in[4];
    float* out = (float*)d_out;
    unsigned short* ws = (unsigned short*)d_ws;

    if (ws_size >= WS_NEED) {
        hipLaunchKernelGGL(transpose_x, dim3(29, GG, 8), dim3(256), 0, stream,
                           x, w_kg, w_pw, ws);
        hipLaunchKernelGGL(invol_mfma, dim3(49, GG, 8), dim3(512), 0, stream,
                           ws, b_kg, b_pw, out);
    } else {
        int pre_blocks = (W_TOTAL + 255) / 256;
        hipLaunchKernelGGL(reorder_weights, dim3(pre_blocks), dim3(256), 0, stream,
                           w_kg, w_pw, ws);
        hipLaunchKernelGGL(invol_mfma_fb, dim3(49, GG, 8), dim3(256), 0, stream,
                           x, b_kg, b_pw, ws, out);
    }
}

// Round 14
// 42.229 us; speedup vs baseline: 3.1191x; 1.1004x over previous
//
#include <hip/hip_runtime.h>
#include <hip/hip_bf16.h>

typedef __attribute__((ext_vector_type(8))) short short8;
typedef __attribute__((ext_vector_type(4))) float f32x4;
typedef __attribute__((ext_vector_type(4))) unsigned int u32x4;

#define GG 4
#define CC 128
#define HH 112
#define WW 112
#define HWSZ (HH * WW)
#define TH 16
#define TW 16
#define HALO 18
#define NPIX (HALO * HALO)      // 324 (fallback LDS tile)
#define XSTR 40                 // fallback LDS pitch
#define HP 114                  // padded spatial dim (1-px zero border)
#define SLICE_PIX (HP * HP)     // 12,996 pixels
#define SLICE_ELE (SLICE_PIX * 32)   // ushorts per (b,g) slice
#define WK_ELEMS (4 * 9 * 16 * 32)   // wk_reord[g][u][t16][c32], taps 9..15 zero
#define WP_ELEMS (4 * 2 * 16 * 32)   // wp_reord[g][mt][o16][c32]
#define W_TOTAL (WK_ELEMS + WP_ELEMS)
#define XT_OFF 32768                 // ushort offset of x_t in ws
#define XT_ELEMS (32 * SLICE_ELE)    // 13,307,904 ushorts = 26.6 MB
#define WS_NEED ((size_t)(XT_OFF + XT_ELEMS) * 2)

__device__ __forceinline__ void reorder_one(int idx,
    const float* __restrict__ w_kg, const float* __restrict__ w_pw,
    unsigned short* __restrict__ ws)
{
    if (idx < WK_ELEMS) {
        int c = idx & 31, t = (idx >> 5) & 15, r = idx >> 9;
        int u = r % 9, g = r / 9;
        float v = (t < 9) ? w_kg[((g * 9 + t) * 32 + c) * 9 + u] : 0.0f;
        ws[idx] = __builtin_bit_cast(unsigned short, __float2bfloat16(v));
    } else if (idx < W_TOTAL) {
        int j = idx - WK_ELEMS;
        int c = j & 31, o = (j >> 5) & 15, mt = (j >> 9) & 1, g = j >> 10;
        float v = w_pw[(g * 32 + mt * 16 + o) * 32 + c];
        ws[idx] = __builtin_bit_cast(unsigned short, __float2bfloat16(v));
    }
}

// ---- standalone weight reorder (fallback path only) ----
__global__ __launch_bounds__(256)
void reorder_weights(const float* __restrict__ w_kg, const float* __restrict__ w_pw,
                     unsigned short* __restrict__ ws)
{
    reorder_one(blockIdx.x * 256 + threadIdx.x, w_kg, w_pw, ws);
}

// ---- transpose x -> x_t[b][g][114x114 pixel][c32] bf16, zero border;
//      hc==28: weight reorder; hc==29: border zeroing ----
__global__ __launch_bounds__(256, 4)
void transpose_x(const float* __restrict__ x,
                 const float* __restrict__ w_kg, const float* __restrict__ w_pw,
                 unsigned short* __restrict__ ws)
{
    __shared__ unsigned int xsT[16 * 452];       // [c2][p448] u32 = 2 channels; 28,928 B
    const int hc = blockIdx.x;                   // 0..27 transpose; 28 weights; 29 border
    const int g = blockIdx.y, b = blockIdx.z;
    const int tid = threadIdx.x;
    const int slice = b * GG + g;
    unsigned short* xt = ws + XT_OFF;

    if (hc == 28) {                              // 32 slices x 704 = 22,528 weight elems
        #pragma unroll
        for (int k = 0; k < 3; ++k) {
            int off = k * 256 + tid;
            if (off < 704)
                reorder_one(slice * 704 + off, w_kg, w_pw, ws);
        }
        return;
    }
    if (hc == 29) {                              // zero the 452 border pixels (64B each)
        unsigned short* xts = xt + (size_t)slice * SLICE_ELE;
        short8 z = {0, 0, 0, 0, 0, 0, 0, 0};
        #pragma unroll
        for (int k = 0; k < 2; ++k) {
            int i = tid + 256 * k;
            if (i < 452) {
                int pix;
                if (i < 114)      pix = i;                       // top row
                else if (i < 228) pix = 113 * HP + (i - 114);    // bottom row
                else if (i < 340) pix = (i - 228 + 1) * HP;      // left col
                else              pix = (i - 340 + 1) * HP + 113;// right col
                unsigned short* d = xts + (size_t)pix * 32;
                *(short8*)(d)      = z;
                *(short8*)(d + 8)  = z;
                *(short8*)(d + 16) = z;
                *(short8*)(d + 24) = z;
            }
        }
        return;
    }

    const float* xg = x + (size_t)(b * CC + g * 32) * HWSZ + hc * 4 * WW;

    // phase 1: coalesced float4 reads (c-major, pixel-fastest), cvt, b16 LDS writes
    unsigned short* xsT16 = (unsigned short*)xsT;
    #pragma unroll
    for (int k = 0; k < 14; ++k) {               // 3584 tasks = 32c x 112 p4-groups
        int t = tid + 256 * k;
        int c = (t * 37450) >> 22;               // t/112, exact for t<3584
        int p4 = t - c * 112;
        float4 v = *(const float4*)(xg + (size_t)c * HWSZ + 4 * p4);
        int base = ((c >> 1) * 452 + 4 * p4) * 2 + (c & 1);
        xsT16[base + 0] = __builtin_bit_cast(unsigned short, __float2bfloat16(v.x));
        xsT16[base + 2] = __builtin_bit_cast(unsigned short, __float2bfloat16(v.y));
        xsT16[base + 4] = __builtin_bit_cast(unsigned short, __float2bfloat16(v.z));
        xsT16[base + 6] = __builtin_bit_cast(unsigned short, __float2bfloat16(v.w));
    }
    __syncthreads();

    // phase 2: gather 4 u32 (8 channels)/pixel, write 16B into padded layout
    unsigned short* xts = xt + (size_t)slice * SLICE_ELE;
    #pragma unroll
    for (int k = 0; k < 7; ++k) {                // 1792 tasks = 448 px x 4 kb-chunks
        int t = tid + 256 * k;
        int p = t >> 2, kb = t & 3;
        int row = p / 112;                       // 0..3 within chunk
        int col = p - 112 * row;
        unsigned r[4];
        #pragma unroll
        for (int j = 0; j < 4; ++j)
            r[j] = xsT[(4 * kb + j) * 452 + p];  // u32 = channels (8kb+2j, 8kb+2j+1)
        size_t pix = (size_t)(hc * 4 + row + 1) * HP + (col + 1);
        *(u32x4*)(xts + pix * 32 + kb * 8) = (u32x4){r[0], r[1], r[2], r[3]};
    }
}

// ---- per-thread weight fragments ----
struct Frags {
    short8 afrag[9];
    short8 wpfrag[2];
    float bkv[4];
    float bpv[8];
};

__device__ __forceinline__ void load_frags(Frags& f,
    const unsigned short* __restrict__ wsw,
    const float* __restrict__ b_kg, const float* __restrict__ b_pw,
    int g, int tid)
{
    const int lane = tid & 63;
    const int px   = lane & 15;
    const int kb   = lane >> 4;

    #pragma unroll
    for (int u = 0; u < 9; ++u)
        f.afrag[u] = *(const short8*)(wsw + (((g * 9 + u) * 16 + px) * 32 + kb * 8));
    #pragma unroll
    for (int mt = 0; mt < 2; ++mt)
        f.wpfrag[mt] = *(const short8*)(wsw + WK_ELEMS + (((g * 2 + mt) * 16 + px) * 32 + kb * 8));

    const float* bk = b_kg + g * 9;
    const float* bp = b_pw + g * 32;
    #pragma unroll
    for (int e = 0; e < 4; ++e) {
        int t = 4 * kb + e;
        f.bkv[e] = bk[t < 9 ? t : 0];   // clamped; invalid taps never consumed
    }
    #pragma unroll
    for (int mt = 0; mt < 2; ++mt)
        #pragma unroll
        for (int e = 0; e < 4; ++e)
            f.bpv[mt * 4 + e] = bp[mt * 16 + 4 * kb + e];
}

// ---- fast main kernel: LDS-FREE B-fragments — direct b128 loads from padded
//      x_t (already in MFMA B layout). No staging, no barrier; only kvl in LDS.
//      (kvl roundtrip kept: ds_bpermute-after-MFMA miscomputes — r5/r9 A/B.) ----
__global__ __launch_bounds__(256, 4)
void invol_mfma(const unsigned short* __restrict__ ws_all,
                const float* __restrict__ b_kg, const float* __restrict__ b_pw,
                float* __restrict__ out)
{
    __shared__ float kvl[4 * 16 * 12];           // 3,072 B only

    const int tile  = blockIdx.x;
    const int tileh = tile / 7;
    const int tilew = tile - tileh * 7;
    const int g = blockIdx.y;
    const int b = blockIdx.z;
    const int h0 = tileh * TH;
    const int w0 = tilew * TW;
    const int tid = threadIdx.x;

    const int lane = tid & 63;
    const int wid  = tid >> 6;
    const int px   = lane & 15;
    const int kb   = lane >> 4;

    Frags f;
    load_frags(f, ws_all, b_kg, b_pw, g, tid);

    const unsigned short* xti = ws_all + XT_OFF + (size_t)(b * GG + g) * SLICE_ELE;
    float* kvp = &kvl[(wid * 16 + px) * 12];
    const size_t obase = ((size_t)(b * CC + g * 32) * HH + h0) * WW + w0 + px;

    #pragma unroll 1
    for (int r = 0; r < 4; ++r) {
        const int py = wid * 4 + r;
        // padded-pixel base for tap (0,0): row h0+py (=gh-1+1), col w0+px
        const int pbase = (h0 + py) * HP + (w0 + px);

        short8 bfrag[9];
        #pragma unroll
        for (int u = 0; u < 9; ++u) {
            int pix = pbase + (u / 3) * HP + (u % 3);
            bfrag[u] = *(const short8*)(xti + (size_t)pix * 32 + kb * 8);
        }

        // stage 1: kv = Wk * P; C/D: col=lane&15 (pixel), row=4*kb+e (tap)
        f32x4 kv = {0.f, 0.f, 0.f, 0.f};
        #pragma unroll
        for (int u = 0; u < 9; ++u)
            kv = __builtin_amdgcn_mfma_f32_16x16x32_bf16(f.afrag[u], bfrag[u], kv, 0, 0, 0);

        // kv cross-lane roundtrip (+bias): lane holds taps 4*kb..4*kb+3 of pixel px
        if (kb < 2) {
            f32x4 kvb;
            #pragma unroll
            for (int i = 0; i < 4; ++i) kvb[i] = kv[i] + f.bkv[i];
            *(f32x4*)&kvp[4 * kb] = kvb;
        } else if (kb == 2) {
            kvp[8] = kv[0] + f.bkv[0];
        }
        __builtin_amdgcn_s_waitcnt(0);           // lgkmcnt(0): kvl writes visible wave-wide
        f32x4 k03 = *(const f32x4*)&kvp[0];
        f32x4 k47 = *(const f32x4*)&kvp[4];
        float k8 = kvp[8];
        float kvv[9] = {k03.x, k03.y, k03.z, k03.w, k47.x, k47.y, k47.z, k47.w, k8};

        // stage 2: involution on VALU, reusing bfrag registers
        float m[8] = {0.f, 0.f, 0.f, 0.f, 0.f, 0.f, 0.f, 0.f};
        #pragma unroll
        for (int u = 0; u < 9; ++u) {
            u32x4 bu = __builtin_bit_cast(u32x4, bfrag[u]);
            #pragma unroll
            for (int w = 0; w < 4; ++w) {
                unsigned d = bu[w];
                float lo = __builtin_bit_cast(float, d << 16);
                float hi = __builtin_bit_cast(float, d & 0xffff0000u);
                m[2 * w]     = fmaf(lo, kvv[u], m[2 * w]);
                m[2 * w + 1] = fmaf(hi, kvv[u], m[2 * w + 1]);
            }
        }

        // stage 3: pointwise via MFMA; m already in B-fragment order (k = 8kb+j)
        unsigned pk[4];
        #pragma unroll
        for (int w = 0; w < 4; ++w) {
            unsigned slo = __builtin_bit_cast(unsigned short, __float2bfloat16(m[2 * w]));
            unsigned shi = __builtin_bit_cast(unsigned short, __float2bfloat16(m[2 * w + 1]));
            pk[w] = slo | (shi << 16);
        }
        short8 mfrag = __builtin_bit_cast(short8, (u32x4){pk[0], pk[1], pk[2], pk[3]});

        f32x4 zero = {0.f, 0.f, 0.f, 0.f};
        f32x4 o0 = __builtin_amdgcn_mfma_f32_16x16x32_bf16(f.wpfrag[0], mfrag, zero, 0, 0, 0);
        f32x4 o1 = __builtin_amdgcn_mfma_f32_16x16x32_bf16(f.wpfrag[1], mfrag, zero, 0, 0, 0);

        #pragma unroll
        for (int e = 0; e < 4; ++e) {
            int o = 4 * kb + e;
            out[obase + (size_t)o * HWSZ + (size_t)py * WW] = o0[e] + f.bpv[e];
            out[obase + (size_t)(o + 16) * HWSZ + (size_t)py * WW] = o1[e] + f.bpv[4 + e];
        }
    }
}

// ---- fallback main kernel (r10-proven: direct fp32 LDS staging) ----
__global__ __launch_bounds__(256, 4)
void invol_mfma_fb(const float* __restrict__ x,
                   const float* __restrict__ b_kg, const float* __restrict__ b_pw,
                   const unsigned short* __restrict__ ws, float* __restrict__ out)
{
    __shared__ unsigned short xs[NPIX * XSTR];
    __shared__ float kvl[4 * 16 * 12];

    const int tile  = blockIdx.x;
    const int tileh = tile / 7;
    const int tilew = tile - tileh * 7;
    const int g = blockIdx.y;
    const int b = blockIdx.z;
    const int h0 = tileh * TH;
    const int w0 = tilew * TW;
    const int tid = threadIdx.x;

    Frags f;
    load_frags(f, ws, b_kg, b_pw, g, tid);

    {
        const float* xg = x + (size_t)(b * CC + g * 32) * HWSZ;
        int c = 0, q = tid;
        #pragma unroll
        for (int batch = 0; batch < 3; ++batch) {
            const int bn = (batch == 2) ? 13 : 14;
            float v[14];
            int pki[14];
            #pragma unroll
            for (int it = 0; it < bn; ++it) {
                const int itg = batch * 14 + it;
                const bool valid = (itg < 40) || (tid < 128);
                int r   = (q * 57) >> 10;
                int col = q - 18 * r;
                int gh = h0 - 1 + r;
                int gw = w0 - 1 + col;
                bool ok = valid && ((unsigned)gh < (unsigned)HH) && ((unsigned)gw < (unsigned)WW);
                int ghc = min(max(gh, 0), HH - 1);
                int gwc = min(max(gw, 0), WW - 1);
                int cc  = min(c, 31);
                float t = xg[(size_t)cc * HWSZ + ghc * WW + gwc];
                v[it]   = ok ? t : 0.0f;
                pki[it] = q * XSTR + c;
                q += 256; if (q >= NPIX) { q -= NPIX; ++c; }
            }
            #pragma unroll
            for (int it = 0; it < bn; ++it)
                xs[pki[it]] = __builtin_bit_cast(unsigned short, __float2bfloat16(v[it]));
        }
    }
    __syncthreads();

    const int lane = tid & 63;
    const int wid  = tid >> 6;
    const int px   = lane & 15;
    const int kb   = lane >> 4;
    float* kvp = &kvl[(wid * 16 + px) * 12];
    const size_t obase = ((size_t)(b * CC + g * 32) * HH + h0) * WW + w0 + px;

    #pragma unroll 1
    for (int r = 0; r < 4; ++r) {
        const int py = wid * 4 + r;
        short8 bfrag[9];
        #pragma unroll
        for (int u = 0; u < 9; ++u) {
            int q = (py + u / 3) * HALO + (px + u % 3);
            bfrag[u] = *(const short8*)&xs[q * XSTR + kb * 8];
        }
        f32x4 kv = {0.f, 0.f, 0.f, 0.f};
        #pragma unroll
        for (int u = 0; u < 9; ++u)
            kv = __builtin_amdgcn_mfma_f32_16x16x32_bf16(f.afrag[u], bfrag[u], kv, 0, 0, 0);
        if (kb < 2) {
            f32x4 kvb;
            #pragma unroll
            for (int i = 0; i < 4; ++i) kvb[i] = kv[i] + f.bkv[i];
            *(f32x4*)&kvp[4 * kb] = kvb;
        } else if (kb == 2) {
            kvp[8] = kv[0] + f.bkv[0];
        }
        f32x4 k03 = *(const f32x4*)&kvp[0];
        f32x4 k47 = *(const f32x4*)&kvp[4];
        float k8 = kvp[8];
        float kvv[9] = {k03.x, k03.y, k03.z, k03.w, k47.x, k47.y, k47.z, k47.w, k8};
        float m[8] = {0.f, 0.f, 0.f, 0.f, 0.f, 0.f, 0.f, 0.f};
        #pragma unroll
        for (int u = 0; u < 9; ++u) {
            u32x4 bu = __builtin_bit_cast(u32x4, bfrag[u]);
            #pragma unroll
            for (int w = 0; w < 4; ++w) {
                unsigned d = bu[w];
                float lo = __builtin_bit_cast(float, d << 16);
                float hi = __builtin_bit_cast(float, d & 0xffff0000u);
                m[2 * w]     = fmaf(lo, kvv[u], m[2 * w]);
                m[2 * w + 1] = fmaf(hi, kvv[u], m[2 * w + 1]);
            }
        }
        unsigned pk[4];
        #pragma unroll
        for (int w = 0; w < 4; ++w) {
            unsigned slo = __builtin_bit_cast(unsigned short, __float2bfloat16(m[2 * w]));
            unsigned shi = __builtin_bit_cast(unsigned short, __float2bfloat16(m[2 * w + 1]));
            pk[w] = slo | (shi << 16);
        }
        short8 mfrag = __builtin_bit_cast(short8, (u32x4){pk[0], pk[1], pk[2], pk[3]});
        f32x4 zero = {0.f, 0.f, 0.f, 0.f};
        f32x4 o0 = __builtin_amdgcn_mfma_f32_16x16x32_bf16(f.wpfrag[0], mfrag, zero, 0, 0, 0);
        f32x4 o1 = __builtin_amdgcn_mfma_f32_16x16x32_bf16(f.wpfrag[1], mfrag, zero, 0, 0, 0);
        #pragma unroll
        for (int e = 0; e < 4; ++e) {
            int o = 4 * kb + e;
            out[obase + (size_t)o * HWSZ + (size_t)py * WW] = o0[e] + f.bpv[e];
            out[obase + (size_t)(o + 16) * HWSZ + (size_t)py * WW] = o1[e] + f.bpv[4 + e];
        }
    }
}

extern "C" void kernel_launch(void* const* d_in, const int* in_sizes, int n_in,
                              void* d_out, int out_size, void* d_ws, size_t ws_size,
                              hipStream_t stream)
{
    const float* x    = (const float*)d_in[0];
    const float* w_kg = (const float*)d_in[1];
    const float* b_kg = (const float*)d_in[2];
    const float* w_pw = (const float*)d_in[3];
    const float* b_pw = (const float*)d_in[4];
    float* out = (float*)d_out;
    unsigned short* ws = (unsigned short*)d_ws;

    if (ws_size >= WS_NEED) {
        hipLaunchKernelGGL(transpose_x, dim3(30, GG, 8), dim3(256), 0, stream,
                           x, w_kg, w_pw, ws);
        hipLaunchKernelGGL(invol_mfma, dim3(49, GG, 8), dim3(256), 0, stream,
                           ws, b_kg, b_pw, out);
    } else {
        int pre_blocks = (W_TOTAL + 255) / 256;
        hipLaunchKernelGGL(reorder_weights, dim3(pre_blocks), dim3(256), 0, stream,
                           w_kg, w_pw, ws);
        hipLaunchKernelGGL(invol_mfma_fb, dim3(49, GG, 8), dim3(256), 0, stream,
                           x, b_kg, b_pw, ws, out);
    }
}

// Round 15
// 35.299 us; speedup vs baseline: 3.7315x; 1.1963x over previous
//
#include <hip/hip_runtime.h>
#include <hip/hip_bf16.h>

typedef __attribute__((ext_vector_type(8))) short short8;
typedef __attribute__((ext_vector_type(4))) float f32x4;
typedef __attribute__((ext_vector_type(4))) unsigned int u32x4;

#define GG 4
#define CC 128
#define HH 112
#define WW 112
#define HWSZ (HH * WW)
#define TH 16
#define TW 16
#define HALO 18
#define NPIX (HALO * HALO)      // 324
#define XSTR 32                 // NO pad: chunk byte = t*16 -> linear global_load_lds dest
#define HP 114                  // padded spatial dim (1-px zero border)
#define SLICE_PIX (HP * HP)
#define SLICE_ELE (SLICE_PIX * 32)
#define WK_ELEMS (4 * 9 * 16 * 32)
#define WP_ELEMS (4 * 2 * 16 * 32)
#define W_TOTAL (WK_ELEMS + WP_ELEMS)
#define XT_OFF 32768
#define XT_ELEMS (32 * SLICE_ELE)
#define WS_NEED ((size_t)(XT_OFF + XT_ELEMS) * 2)

__device__ __forceinline__ void reorder_one(int idx,
    const float* __restrict__ w_kg, const float* __restrict__ w_pw,
    unsigned short* __restrict__ ws)
{
    if (idx < WK_ELEMS) {
        int c = idx & 31, t = (idx >> 5) & 15, r = idx >> 9;
        int u = r % 9, g = r / 9;
        float v = (t < 9) ? w_kg[((g * 9 + t) * 32 + c) * 9 + u] : 0.0f;
        ws[idx] = __builtin_bit_cast(unsigned short, __float2bfloat16(v));
    } else if (idx < W_TOTAL) {
        int j = idx - WK_ELEMS;
        int c = j & 31, o = (j >> 5) & 15, mt = (j >> 9) & 1, g = j >> 10;
        float v = w_pw[(g * 32 + mt * 16 + o) * 32 + c];
        ws[idx] = __builtin_bit_cast(unsigned short, __float2bfloat16(v));
    }
}

__global__ __launch_bounds__(256)
void reorder_weights(const float* __restrict__ w_kg, const float* __restrict__ w_pw,
                     unsigned short* __restrict__ ws)
{
    reorder_one(blockIdx.x * 256 + threadIdx.x, w_kg, w_pw, ws);
}

// ---- transpose x -> padded x_t[b][g][114x114][c32] bf16 (r14-proven);
//      hc==28: weights; hc==29: zero border ----
__global__ __launch_bounds__(256, 4)
void transpose_x(const float* __restrict__ x,
                 const float* __restrict__ w_kg, const float* __restrict__ w_pw,
                 unsigned short* __restrict__ ws)
{
    __shared__ unsigned int xsT[16 * 452];
    const int hc = blockIdx.x;
    const int g = blockIdx.y, b = blockIdx.z;
    const int tid = threadIdx.x;
    const int slice = b * GG + g;
    unsigned short* xt = ws + XT_OFF;

    if (hc == 28) {
        #pragma unroll
        for (int k = 0; k < 3; ++k) {
            int off = k * 256 + tid;
            if (off < 704)
                reorder_one(slice * 704 + off, w_kg, w_pw, ws);
        }
        return;
    }
    if (hc == 29) {
        unsigned short* xts = xt + (size_t)slice * SLICE_ELE;
        short8 z = {0, 0, 0, 0, 0, 0, 0, 0};
        #pragma unroll
        for (int k = 0; k < 2; ++k) {
            int i = tid + 256 * k;
            if (i < 452) {
                int pix;
                if (i < 114)      pix = i;
                else if (i < 228) pix = 113 * HP + (i - 114);
                else if (i < 340) pix = (i - 228 + 1) * HP;
                else              pix = (i - 340 + 1) * HP + 113;
                unsigned short* d = xts + (size_t)pix * 32;
                *(short8*)(d)      = z;
                *(short8*)(d + 8)  = z;
                *(short8*)(d + 16) = z;
                *(short8*)(d + 24) = z;
            }
        }
        return;
    }

    const float* xg = x + (size_t)(b * CC + g * 32) * HWSZ + hc * 4 * WW;

    unsigned short* xsT16 = (unsigned short*)xsT;
    #pragma unroll
    for (int k = 0; k < 14; ++k) {
        int t = tid + 256 * k;
        int c = (t * 37450) >> 22;
        int p4 = t - c * 112;
        float4 v = *(const float4*)(xg + (size_t)c * HWSZ + 4 * p4);
        int base = ((c >> 1) * 452 + 4 * p4) * 2 + (c & 1);
        xsT16[base + 0] = __builtin_bit_cast(unsigned short, __float2bfloat16(v.x));
        xsT16[base + 2] = __builtin_bit_cast(unsigned short, __float2bfloat16(v.y));
        xsT16[base + 4] = __builtin_bit_cast(unsigned short, __float2bfloat16(v.z));
        xsT16[base + 6] = __builtin_bit_cast(unsigned short, __float2bfloat16(v.w));
    }
    __syncthreads();

    unsigned short* xts = xt + (size_t)slice * SLICE_ELE;
    #pragma unroll
    for (int k = 0; k < 7; ++k) {
        int t = tid + 256 * k;
        int p = t >> 2, kb = t & 3;
        int row = p / 112;
        int col = p - 112 * row;
        unsigned r[4];
        #pragma unroll
        for (int j = 0; j < 4; ++j)
            r[j] = xsT[(4 * kb + j) * 452 + p];
        size_t pix = (size_t)(hc * 4 + row + 1) * HP + (col + 1);
        *(u32x4*)(xts + pix * 32 + kb * 8) = (u32x4){r[0], r[1], r[2], r[3]};
    }
}

// ---- per-thread weight fragments ----
struct Frags {
    short8 afrag[9];
    short8 wpfrag[2];
    float bkv[4];
    float bpv[8];
};

__device__ __forceinline__ void load_frags(Frags& f,
    const unsigned short* __restrict__ wsw,
    const float* __restrict__ b_kg, const float* __restrict__ b_pw,
    int g, int tid)
{
    const int lane = tid & 63;
    const int px   = lane & 15;
    const int kb   = lane >> 4;

    #pragma unroll
    for (int u = 0; u < 9; ++u)
        f.afrag[u] = *(const short8*)(wsw + (((g * 9 + u) * 16 + px) * 32 + kb * 8));
    #pragma unroll
    for (int mt = 0; mt < 2; ++mt)
        f.wpfrag[mt] = *(const short8*)(wsw + WK_ELEMS + (((g * 2 + mt) * 16 + px) * 32 + kb * 8));

    const float* bk = b_kg + g * 9;
    const float* bp = b_pw + g * 32;
    #pragma unroll
    for (int e = 0; e < 4; ++e) {
        int t = 4 * kb + e;
        f.bkv[e] = bk[t < 9 ? t : 0];
    }
    #pragma unroll
    for (int mt = 0; mt < 2; ++mt)
        #pragma unroll
        for (int e = 0; e < 4; ++e)
            f.bpv[mt * 4 + e] = bp[mt * 16 + 4 * kb + e];
}

// ---- r10-proven compute body (kvl roundtrip; NO ds_bpermute; no explicit waitcnt) ----
__device__ __forceinline__ void compute_tile(const Frags& f,
    float* __restrict__ out, unsigned short* xs, float* kvl,
    int g, int b, int h0, int w0, int tid)
{
    const int lane = tid & 63;
    const int wid  = tid >> 6;
    const int px   = lane & 15;
    const int kb   = lane >> 4;

    float* kvp = &kvl[(wid * 16 + px) * 12];
    const size_t obase = ((size_t)(b * CC + g * 32) * HH + h0) * WW + w0 + px;

    #pragma unroll 1
    for (int r = 0; r < 4; ++r) {
        const int py = wid * 4 + r;

        short8 bfrag[9];
        #pragma unroll
        for (int u = 0; u < 9; ++u) {
            int q = (py + u / 3) * HALO + (px + u % 3);
            bfrag[u] = *(const short8*)&xs[q * XSTR + kb * 8];
        }

        f32x4 kv = {0.f, 0.f, 0.f, 0.f};
        #pragma unroll
        for (int u = 0; u < 9; ++u)
            kv = __builtin_amdgcn_mfma_f32_16x16x32_bf16(f.afrag[u], bfrag[u], kv, 0, 0, 0);

        if (kb < 2) {
            f32x4 kvb;
            #pragma unroll
            for (int i = 0; i < 4; ++i) kvb[i] = kv[i] + f.bkv[i];
            *(f32x4*)&kvp[4 * kb] = kvb;
        } else if (kb == 2) {
            kvp[8] = kv[0] + f.bkv[0];
        }
        f32x4 k03 = *(const f32x4*)&kvp[0];
        f32x4 k47 = *(const f32x4*)&kvp[4];
        float k8 = kvp[8];
        float kvv[9] = {k03.x, k03.y, k03.z, k03.w, k47.x, k47.y, k47.z, k47.w, k8};

        float m[8] = {0.f, 0.f, 0.f, 0.f, 0.f, 0.f, 0.f, 0.f};
        #pragma unroll
        for (int u = 0; u < 9; ++u) {
            u32x4 bu = __builtin_bit_cast(u32x4, bfrag[u]);
            #pragma unroll
            for (int w = 0; w < 4; ++w) {
                unsigned d = bu[w];
                float lo = __builtin_bit_cast(float, d << 16);
                float hi = __builtin_bit_cast(float, d & 0xffff0000u);
                m[2 * w]     = fmaf(lo, kvv[u], m[2 * w]);
                m[2 * w + 1] = fmaf(hi, kvv[u], m[2 * w + 1]);
            }
        }

        unsigned pk[4];
        #pragma unroll
        for (int w = 0; w < 4; ++w) {
            unsigned slo = __builtin_bit_cast(unsigned short, __float2bfloat16(m[2 * w]));
            unsigned shi = __builtin_bit_cast(unsigned short, __float2bfloat16(m[2 * w + 1]));
            pk[w] = slo | (shi << 16);
        }
        short8 mfrag = __builtin_bit_cast(short8, (u32x4){pk[0], pk[1], pk[2], pk[3]});

        f32x4 zero = {0.f, 0.f, 0.f, 0.f};
        f32x4 o0 = __builtin_amdgcn_mfma_f32_16x16x32_bf16(f.wpfrag[0], mfrag, zero, 0, 0, 0);
        f32x4 o1 = __builtin_amdgcn_mfma_f32_16x16x32_bf16(f.wpfrag[1], mfrag, zero, 0, 0, 0);

        #pragma unroll
        for (int e = 0; e < 4; ++e) {
            int o = 4 * kb + e;
            out[obase + (size_t)o * HWSZ + (size_t)py * WW] = o0[e] + f.bpv[e];
            out[obase + (size_t)(o + 16) * HWSZ + (size_t)py * WW] = o1[e] + f.bpv[4 + e];
        }
    }
}

// ---- fast main kernel: global_load_lds DMA staging from padded x_t ----
__global__ __launch_bounds__(256, 4)
void invol_mfma(const unsigned short* __restrict__ ws_all,
                const float* __restrict__ b_kg, const float* __restrict__ b_pw,
                float* __restrict__ out)
{
    __shared__ unsigned short xs[NPIX * XSTR];   // 20,736 B, linear: chunk t at byte t*16
    __shared__ float kvl[4 * 16 * 12];           //  3,072 B -> 6 blocks/CU

    const int tile  = blockIdx.x;
    const int tileh = tile / 7;
    const int tilew = tile - tileh * 7;
    const int g = blockIdx.y;
    const int b = blockIdx.z;
    const int h0 = tileh * TH;
    const int w0 = tilew * TW;
    const int tid = threadIdx.x;

    Frags f;
    load_frags(f, ws_all, b_kg, b_pw, g, tid);

    // staging: 1296 x 16B async DMA chunks. LDS dest byte = t*16 (uniform base +
    // lane*16 per wave-instr — HW requirement); source per-lane in padded x_t
    // (zero border -> no masking needed).
    {
        const unsigned short* xti = ws_all + XT_OFF + (size_t)(b * GG + g) * SLICE_ELE;
        #pragma unroll
        for (int k = 0; k < 6; ++k) {
            int t = tid + 256 * k;
            if (t < 1296) {
                int q = t >> 2, kb2 = t & 3;
                int r = (q * 57) >> 10;          // q/18 for q<324
                int col = q - 18 * r;
                const unsigned short* src =
                    xti + ((size_t)((h0 + r) * HP + (w0 + col)) * 32 + kb2 * 8);
                __builtin_amdgcn_global_load_lds(src, &xs[t * 8], 16, 0, 0);
            }
        }
    }
    __syncthreads();   // drains vmcnt (DMA + frag loads) before compute

    compute_tile(f, out, xs, kvl, g, b, h0, w0, tid);
}

// ---- fallback main kernel (direct fp32 staging) for small ws ----
__global__ __launch_bounds__(256, 4)
void invol_mfma_fb(const float* __restrict__ x,
                   const float* __restrict__ b_kg, const float* __restrict__ b_pw,
                   const unsigned short* __restrict__ ws, float* __restrict__ out)
{
    __shared__ unsigned short xs[NPIX * XSTR];
    __shared__ float kvl[4 * 16 * 12];

    const int tile  = blockIdx.x;
    const int tileh = tile / 7;
    const int tilew = tile - tileh * 7;
    const int g = blockIdx.y;
    const int b = blockIdx.z;
    const int h0 = tileh * TH;
    const int w0 = tilew * TW;
    const int tid = threadIdx.x;

    Frags f;
    load_frags(f, ws, b_kg, b_pw, g, tid);

    {
        const float* xg = x + (size_t)(b * CC + g * 32) * HWSZ;
        int c = 0, q = tid;
        #pragma unroll
        for (int batch = 0; batch < 3; ++batch) {
            const int bn = (batch == 2) ? 13 : 14;
            float v[14];
            int pki[14];
            #pragma unroll
            for (int it = 0; it < bn; ++it) {
                const int itg = batch * 14 + it;
                const bool valid = (itg < 40) || (tid < 128);
                int r   = (q * 57) >> 10;
                int col = q - 18 * r;
                int gh = h0 - 1 + r;
                int gw = w0 - 1 + col;
                bool ok = valid && ((unsigned)gh < (unsigned)HH) && ((unsigned)gw < (unsigned)WW);
                int ghc = min(max(gh, 0), HH - 1);
                int gwc = min(max(gw, 0), WW - 1);
                int cc  = min(c, 31);
                float t = xg[(size_t)cc * HWSZ + ghc * WW + gwc];
                v[it]   = ok ? t : 0.0f;
                pki[it] = (c < 32) ? (q * XSTR + c) : 0;
                q += 256; if (q >= NPIX) { q -= NPIX; ++c; }
            }
            #pragma unroll
            for (int it = 0; it < bn; ++it) {
                unsigned short val = __builtin_bit_cast(unsigned short, __float2bfloat16(v[it]));
                if (pki[it] || it == 0) xs[pki[it]] = val;   // c==32 items skipped
            }
        }
    }
    __syncthreads();

    compute_tile(f, out, xs, kvl, g, b, h0, w0, tid);
}

extern "C" void kernel_launch(void* const* d_in, const int* in_sizes, int n_in,
                              void* d_out, int out_size, void* d_ws, size_t ws_size,
                              hipStream_t stream)
{
    const float* x    = (const float*)d_in[0];
    const float* w_kg = (const float*)d_in[1];
    const float* b_kg = (const float*)d_in[2];
    const float* w_pw = (const float*)d_in[3];
    const float* b_pw = (const float*)d_in[4];
    float* out = (float*)d_out;
    unsigned short* ws = (unsigned short*)d_ws;

    if (ws_size >= WS_NEED) {
        hipLaunchKernelGGL(transpose_x, dim3(30, GG, 8), dim3(256), 0, stream,
                           x, w_kg, w_pw, ws);
        hipLaunchKernelGGL(invol_mfma, dim3(49, GG, 8), dim3(256), 0, stream,
                           ws, b_kg, b_pw, out);
    } else {
        int pre_blocks = (W_TOTAL + 255) / 256;
        hipLaunchKernelGGL(reorder_weights, dim3(pre_blocks), dim3(256), 0, stream,
                           w_kg, w_pw, ws);
        hipLaunchKernelGGL(invol_mfma_fb, dim3(49, GG, 8), dim3(256), 0, stream,
                           x, b_kg, b_pw, ws, out);
    }
}